// Round 3
// baseline (3457.461 us; speedup 1.0000x reference)
//
#include <hip/hip_runtime.h>
#include <hip/hip_bf16.h>

#define N_ATOMS 400000
#define MAX_D   4
#define NDEG_   5
#define B_GR    16384
#define NTASK   12
#define AT      256                 // atoms per affine tile (= block size); bins aligned to AT
#define PADCAP  401408              // 1568 * 256 >= N + 5*(AT-1)
#define NSCR_FLOATS (PADCAP * 20)   // neighbor-sum scratch (32.1 MB)

__device__ __forceinline__ float selu_f(float x) {
    const float a = 1.6732632423543772f, s = 1.0507009873554805f;
    return x > 0.f ? s * x : s * a * (__expf(x) - 1.f);
}

// ===================== degree-sort prep =====================
// ctr layout (ints): [0..4] counts, [5..9] cursor, [10..15] bin offsets
__global__ void zero_kernel(int* ctr) {
    if (threadIdx.x < 10) ctr[threadIdx.x] = 0;
}

__launch_bounds__(256)
__global__ void fill_kernel(int* idx, int* degs_s) {
    const int e = blockIdx.x * 256 + threadIdx.x;
    if (e < PADCAP) { idx[e] = -1; degs_s[e] = -1; }
}

__launch_bounds__(256)
__global__ void hist_kernel(const int* __restrict__ deg, int* ctr) {
    __shared__ int h[NDEG_];
    if (threadIdx.x < NDEG_) h[threadIdx.x] = 0;
    __syncthreads();
    for (int i = blockIdx.x * 256 + threadIdx.x; i < N_ATOMS; i += gridDim.x * 256)
        atomicAdd(&h[deg[i]], 1);
    __syncthreads();
    if (threadIdx.x < NDEG_ && h[threadIdx.x]) atomicAdd(&ctr[threadIdx.x], h[threadIdx.x]);
}

__global__ void offsets_kernel(int* ctr) {
    if (threadIdx.x == 0) {
        int run = 0;
        for (int d = 0; d < NDEG_; ++d) {
            ctr[10 + d] = run;
            run += ctr[d];
            run = (run + AT - 1) & ~(AT - 1);
        }
        ctr[15] = run;
    }
}

__launch_bounds__(256)
__global__ void scatter_kernel(const int* __restrict__ deg, int* ctr,
                               int* idx, int* rank, int* degs_s) {
    const int i = blockIdx.x * 256 + threadIdx.x;
    if (i >= N_ATOMS) return;
    const int d = deg[i];
    const int pos = atomicAdd(&ctr[5 + d], 1);
    const int p = ctr[10 + d] + pos;
    idx[p] = i;
    rank[i] = p;
    degs_s[p] = d;
}

__launch_bounds__(256)
__global__ void nbrprep_kernel(const int* __restrict__ nbr, const int* __restrict__ rank,
                               int4* __restrict__ nbrs_s) {
    const int i = blockIdx.x * 256 + threadIdx.x;
    if (i >= N_ATOMS) return;
    const int p = rank[i];
    const int4 nb = *reinterpret_cast<const int4*>(nbr + (size_t)i * MAX_D);
    nbrs_s[p] = make_int4(rank[nb.x], rank[nb.y], rank[nb.z], rank[nb.w]);
}

// ===================== gather: masked neighbor sum (sorted space) =====================
// nsum[p - p0][f] = sum_{j < deg} x[nbrs_s[p][j]][f]   (x in sorted layout; FIRST: af atom-major)
template<int FI, bool FIRST>
__launch_bounds__(256)
__global__ void gather_s(const float* __restrict__ x,
                         const int4*  __restrict__ nbrs,
                         const int*   __restrict__ degs_s,
                         const int*   __restrict__ idx,
                         float*       __restrict__ nsum,
                         int p0, int total /* = cnt*FI */)
{
    for (int e = blockIdx.x * 256 + threadIdx.x; e < total; e += gridDim.x * 256) {
        const int pl = e / FI, f = e - pl * FI;
        const int p = p0 + pl;
        const int d = degs_s[p];
        float s = 0.f;
        if (d > 0) {
            const int4 nb = nbrs[p];
            if (FIRST) {
                s += x[(size_t)idx[nb.x] * FI + f];
                if (d > 1) s += x[(size_t)idx[nb.y] * FI + f];
                if (d > 2) s += x[(size_t)idx[nb.z] * FI + f];
                if (d > 3) s += x[(size_t)idx[nb.w] * FI + f];
            } else {
                s += x[(size_t)nb.x * FI + f];
                if (d > 1) s += x[(size_t)nb.y * FI + f];
                if (d > 2) s += x[(size_t)nb.z * FI + f];
                if (d > 3) s += x[(size_t)nb.w * FI + f];
            }
        }
        nsum[e] = s;
    }
}

// ===================== affine: out_s[p] = selu(x@Ws[d] + nsum@Wn[d] + b[d]) =====================
// Degree-uniform tiles (bins AT-aligned). Weights read through a wave-uniform
// pointer -> scalar loads feeding v_fma directly. No LDS. acc[FO] in registers.
template<int FI, int FO, bool FIRST>
__launch_bounds__(256)
__global__ void affine_s(const float* __restrict__ x,
                         const float* __restrict__ nsum,
                         const float* __restrict__ Ws,
                         const float* __restrict__ Wn,
                         const float* __restrict__ bias,
                         const int*   __restrict__ degs_s,
                         const int*   __restrict__ idx,
                         float*       __restrict__ outs,
                         int p0)
{
    const int tile_base = p0 + blockIdx.x * AT;
    const int dfirst = degs_s[tile_base];
    if (dfirst < 0) return;                       // whole tile is padding
    const int d = __builtin_amdgcn_readfirstlane(dfirst);

    const float* __restrict__ wsd = Ws + d * FI * FO;
    const float* __restrict__ wnd = Wn + d * FI * FO;
    const float* __restrict__ bb  = bias + d * FO;

    const int p = tile_base + threadIdx.x;

    float acc[FO];
    #pragma unroll
    for (int o = 0; o < FO; ++o) acc[o] = bb[o];

    const float* __restrict__ xr;
    if (FIRST) {
        int a = idx[p];
        if (a < 0) a = 0;                         // padding lane: dummy row, result discarded
        xr = x + (size_t)a * FI;
    } else {
        xr = x + (size_t)p * FI;
    }
    const float* __restrict__ nr = nsum + (size_t)(p - p0) * FI;

    for (int f = 0; f < FI; ++f) {
        const float xv = xr[f];
        const float nv = nr[f];
        const float* __restrict__ wsf = wsd + f * FO;
        const float* __restrict__ wnf = wnd + f * FO;
        #pragma unroll
        for (int o = 0; o < FO; ++o)
            acc[o] = fmaf(xv, wsf[o], fmaf(nv, wnf[o], acc[o]));
    }

    float* __restrict__ orow = outs + (size_t)p * FO;
    #pragma unroll
    for (int o = 0; o < FO; ++o) orow[o] = selu_f(acc[o]);
}

template<int FI, int FO, bool FIRST>
static void run_conv(const float* x, const float* Ws, const float* Wn, const float* b,
                     const int4* nbrs_s, const int* degs_s, const int* idx,
                     float* outs, float* nscr, hipStream_t stream)
{
    const int cap = ((NSCR_FLOATS / FI) / AT) * AT;   // atoms per chunk (multiple of AT)
    for (int p0 = 0; p0 < PADCAP; p0 += cap) {
        const int cnt = (PADCAP - p0) < cap ? (PADCAP - p0) : cap;
        const int gtot = cnt * FI;
        int gblocks = (gtot + 255) / 256; if (gblocks > 8192) gblocks = 8192;
        gather_s<FI, FIRST><<<gblocks, 256, 0, stream>>>(x, nbrs_s, degs_s, idx, nscr, p0, gtot);
        affine_s<FI, FO, FIRST><<<cnt / AT, AT, 0, stream>>>(x, nscr, Ws, Wn, b, degs_s, idx, outs, p0);
    }
}

// ===================== GraphGather readout + softmax head =====================
__launch_bounds__(64)
__global__ void readout_kernel(const float* __restrict__ x4s,
                               const int*   __restrict__ rank,
                               const int*   __restrict__ mem,
                               const float* __restrict__ Wd2,
                               const float* __restrict__ bd2,
                               float*       __restrict__ p)
{
    const int g = blockIdx.x;
    const int t = threadIdx.x;

    int lo = 0, hi = N_ATOMS;                    // lower_bound(g)
    while (lo < hi) { int mid = (lo + hi) >> 1; if (mem[mid] < g) lo = mid + 1; else hi = mid; }
    int lo2 = lo, hi2 = N_ATOMS;                 // lower_bound(g+1)
    while (lo2 < hi2) { int mid = (lo2 + hi2) >> 1; if (mem[mid] < g + 1) lo2 = mid + 1; else hi2 = mid; }

    __shared__ float r[72];
    if (t < 36) {
        float s = 0.f, m = -3.4e38f;
        for (int a = lo; a < lo2; ++a) {
            const int rr = rank[a];
            float v = x4s[(size_t)rr * 36 + t];
            s += v;
            m = fmaxf(m, v);
        }
        if (lo2 == lo) m = 0.f;                  // empty graph -> 0
        r[t]      = selu_f(s);
        r[36 + t] = selu_f(m);
    }
    __syncthreads();
    if (t < 24) {
        float acc = bd2[t];
        #pragma unroll
        for (int f = 0; f < 72; ++f) acc += r[f] * Wd2[f * 24 + t];
        float part = __shfl_xor(acc, 1);
        p[g * 24 + t] = 1.f / (1.f + __expf(part - acc));
    }
}

__launch_bounds__(256)
__global__ void dense1_kernel(const float* __restrict__ p,
                              const float* __restrict__ Wl1,
                              const float* __restrict__ bl1,
                              float*       __restrict__ y1)
{
    const int idx = blockIdx.x * 256 + threadIdx.x;
    if (idx >= B_GR * 96) return;
    const int row = idx / 96, c = idx - row * 96;
    float acc = bl1[c];
    const float* pr = p + row * 24;
    #pragma unroll
    for (int f = 0; f < 24; ++f) acc += pr[f] * Wl1[f * 96 + c];
    y1[idx] = acc;
}

template<int C>
__launch_bounds__(256)
__global__ void stats_kernel(const float* __restrict__ y, float* __restrict__ st)
{
    const int c = blockIdx.x;
    float s = 0.f, q = 0.f;
    for (int r = threadIdx.x; r < B_GR; r += 256) {
        const float v = y[r * C + c];
        s += v; q += v * v;
    }
    __shared__ float ss[256], qq[256];
    ss[threadIdx.x] = s; qq[threadIdx.x] = q;
    __syncthreads();
    for (int off = 128; off > 0; off >>= 1) {
        if (threadIdx.x < off) {
            ss[threadIdx.x] += ss[threadIdx.x + off];
            qq[threadIdx.x] += qq[threadIdx.x + off];
        }
        __syncthreads();
    }
    if (threadIdx.x == 0) {
        const float mean = ss[0] / (float)B_GR;
        const float var  = qq[0] / (float)B_GR - mean * mean;
        st[c]     = mean;
        st[C + c] = rsqrtf(var + 1e-5f);
    }
}

__launch_bounds__(256)
__global__ void dense2_kernel(const float* __restrict__ y1,
                              const float* __restrict__ st1,
                              const float* __restrict__ g1,
                              const float* __restrict__ be1,
                              const float* __restrict__ Wl2,
                              const float* __restrict__ bl2,
                              float*       __restrict__ y2)
{
    __shared__ float h[4 * 96];
    const int r0 = blockIdx.x * 4;
    for (int e = threadIdx.x; e < 4 * 96; e += 256) {
        const int rr = e / 96, c = e - rr * 96;
        float v = y1[(r0 + rr) * 96 + c];
        v = (v - st1[c]) * st1[96 + c] * g1[c] + be1[c];
        h[e] = fmaxf(v, 0.f);
    }
    __syncthreads();
    for (int e = threadIdx.x; e < 4 * 63; e += 256) {
        const int rr = e / 63, o = e - rr * 63;
        float acc = bl2[o];
        #pragma unroll
        for (int f = 0; f < 96; ++f) acc += h[rr * 96 + f] * Wl2[f * 63 + o];
        y2[(r0 + rr) * 63 + o] = acc;
    }
}

__launch_bounds__(320)
__global__ void dense3_kernel(const float* __restrict__ y2,
                              const float* __restrict__ st2,
                              const float* __restrict__ g2,
                              const float* __restrict__ be2,
                              const float* __restrict__ Wl3,
                              const float* __restrict__ bl3,
                              float*       __restrict__ out)
{
    __shared__ float h[2 * 63];
    const int r0 = blockIdx.x * 2;
    for (int e = threadIdx.x; e < 2 * 63; e += 320) {
        const int rr = e / 63, c = e - rr * 63;
        float v = y2[(r0 + rr) * 63 + c];
        v = (v - st2[c]) * st2[63 + c] * g2[c] + be2[c];
        h[e] = fmaxf(v, 0.f);
    }
    __syncthreads();
    for (int e = threadIdx.x; e < 2 * 138; e += 320) {
        const int rr = e / 138, o = e - rr * 138;
        float acc = bl3[o];
        #pragma unroll
        for (int f = 0; f < 63; ++f) acc += h[rr * 63 + f] * Wl3[f * 138 + o];
        out[(r0 + rr) * 138 + o] = 1.f / (1.f + __expf(-acc));
    }
}

extern "C" void kernel_launch(void* const* d_in, const int* in_sizes, int n_in,
                              void* d_out, int out_size, void* d_ws, size_t ws_size,
                              hipStream_t stream)
{
    (void)in_sizes; (void)n_in; (void)out_size; (void)ws_size;

    const float* af  = (const float*)d_in[0];
    const float* Ws1 = (const float*)d_in[1];
    const float* Wn1 = (const float*)d_in[2];
    const float* b1  = (const float*)d_in[3];
    const float* Ws2 = (const float*)d_in[4];
    const float* Wn2 = (const float*)d_in[5];
    const float* b2  = (const float*)d_in[6];
    const float* Ws3 = (const float*)d_in[7];
    const float* Wn3 = (const float*)d_in[8];
    const float* b3  = (const float*)d_in[9];
    const float* Ws4 = (const float*)d_in[10];
    const float* Wn4 = (const float*)d_in[11];
    const float* b4  = (const float*)d_in[12];
    const float* Wd2 = (const float*)d_in[13];
    const float* bd2 = (const float*)d_in[14];
    const float* Wl1 = (const float*)d_in[15];
    const float* bl1 = (const float*)d_in[16];
    const float* g1  = (const float*)d_in[17];
    const float* be1 = (const float*)d_in[18];
    const float* Wl2 = (const float*)d_in[19];
    const float* bl2 = (const float*)d_in[20];
    const float* g2  = (const float*)d_in[21];
    const float* be2 = (const float*)d_in[22];
    const float* Wl3 = (const float*)d_in[23];
    const float* bl3 = (const float*)d_in[24];
    const int*   nbr = (const int*)d_in[25];
    const int*   deg = (const int*)d_in[26];
    const int*   mem = (const int*)d_in[27];

    float* ws = (float*)d_ws;
    // float-slot layout
    float* bufA = ws;                                   // PADCAP*27 = 10,838,016
    float* bufB = bufA + (size_t)PADCAP * 27;           // PADCAP*36 = 14,450,688
    float* nscr = bufB + (size_t)PADCAP * 36;           // NSCR_FLOATS = 8,028,160
    int*   idx    = (int*)(nscr + NSCR_FLOATS);         // PADCAP
    int*   rank   = idx + PADCAP;                       // N_ATOMS
    int*   degs_s = rank + N_ATOMS;                     // PADCAP
    int4*  nbrs_s = (int4*)(degs_s + PADCAP);           // PADCAP int4
    int*   ctr    = (int*)(nbrs_s + PADCAP);            // 16 ints

    float* x1 = bufA;
    float* x2 = bufB;
    float* x3 = bufA;
    float* x4 = bufB;
    float* p   = bufA;                       // B*24  (x3 dead after conv4)
    float* y1  = bufA + 393216;              // B*96
    float* y2  = bufA + 393216 + 1572864;    // B*63
    float* st1 = bufA + 393216 + 1572864 + 1032192;     // 192
    float* st2 = st1 + 192;                              // 126

    // ---- degree-sort prep (permutation may vary run-to-run; per-atom math identical) ----
    zero_kernel<<<1, 16, 0, stream>>>(ctr);
    fill_kernel<<<PADCAP / 256, 256, 0, stream>>>(idx, degs_s);
    hist_kernel<<<1024, 256, 0, stream>>>(deg, ctr);
    offsets_kernel<<<1, 1, 0, stream>>>(ctr);
    scatter_kernel<<<(N_ATOMS + 255) / 256, 256, 0, stream>>>(deg, ctr, idx, rank, degs_s);
    nbrprep_kernel<<<(N_ATOMS + 255) / 256, 256, 0, stream>>>(nbr, rank, nbrs_s);

    // ---- conv stack (sorted feature space) ----
    run_conv<75, 15, true >(af, Ws1, Wn1, b1, nbrs_s, degs_s, idx, x1, nscr, stream);
    run_conv<15, 20, false>(x1, Ws2, Wn2, b2, nbrs_s, degs_s, idx, x2, nscr, stream);
    run_conv<20, 27, false>(x2, Ws3, Wn3, b3, nbrs_s, degs_s, idx, x3, nscr, stream);
    run_conv<27, 36, false>(x3, Ws4, Wn4, b4, nbrs_s, degs_s, idx, x4, nscr, stream);

    readout_kernel<<<B_GR, 64, 0, stream>>>(x4, rank, mem, Wd2, bd2, p);

    dense1_kernel<<<(B_GR * 96) / 256, 256, 0, stream>>>(p, Wl1, bl1, y1);
    stats_kernel<96><<<96, 256, 0, stream>>>(y1, st1);
    dense2_kernel<<<B_GR / 4, 256, 0, stream>>>(y1, st1, g1, be1, Wl2, bl2, y2);
    stats_kernel<63><<<63, 256, 0, stream>>>(y2, st2);
    dense3_kernel<<<B_GR / 2, 320, 0, stream>>>(y2, st2, g2, be2, Wl3, bl3, (float*)d_out);
}

// Round 4
// 1107.964 us; speedup vs baseline: 3.1206x; 3.1206x over previous
//
#include <hip/hip_runtime.h>
#include <hip/hip_bf16.h>

#define N_ATOMS 400000
#define MAX_D   4
#define NDEG_   5
#define B_GR    16384
#define NTASK   12
#define AT      256                 // atoms per affine tile (= block size); bins aligned to AT
#define PADCAP  401408              // 1568 * 256 >= N + 5*(AT-1)
#define NSCR_FLOATS (PADCAP * 20)   // neighbor-sum scratch (32.1 MB)

__device__ __forceinline__ float selu_f(float x) {
    const float a = 1.6732632423543772f, s = 1.0507009873554805f;
    return x > 0.f ? s * x : s * a * (__expf(x) - 1.f);
}

// ===================== degree-sort prep =====================
// ctr layout (ints): [0..4] counts, [5..9] cursor, [10..15] bin offsets
__global__ void zero_kernel(int* ctr) {
    if (threadIdx.x < 10) ctr[threadIdx.x] = 0;
}

__launch_bounds__(256)
__global__ void fill_kernel(int* idx, int* degs_s) {
    const int e = blockIdx.x * 256 + threadIdx.x;
    if (e < PADCAP) { idx[e] = -1; degs_s[e] = -1; }
}

__launch_bounds__(256)
__global__ void hist_kernel(const int* __restrict__ deg, int* ctr) {
    __shared__ int h[NDEG_];
    if (threadIdx.x < NDEG_) h[threadIdx.x] = 0;
    __syncthreads();
    for (int i = blockIdx.x * 256 + threadIdx.x; i < N_ATOMS; i += gridDim.x * 256)
        atomicAdd(&h[deg[i]], 1);
    __syncthreads();
    if (threadIdx.x < NDEG_ && h[threadIdx.x]) atomicAdd(&ctr[threadIdx.x], h[threadIdx.x]);
}

__global__ void offsets_kernel(int* ctr) {
    if (threadIdx.x == 0) {
        int run = 0;
        for (int d = 0; d < NDEG_; ++d) {
            ctr[10 + d] = run;
            run += ctr[d];
            run = (run + AT - 1) & ~(AT - 1);
        }
        ctr[15] = run;
    }
}

// Hierarchical scatter: per-block LDS histogram -> ONE global atomicAdd per
// (block, degree) -> intra-block rank from LDS counter. ~7.8k global atomics
// instead of 400k (which serialized 2.4 ms on 5 cache lines).
__launch_bounds__(256)
__global__ void scatter_kernel(const int* __restrict__ deg, int* ctr,
                               int* idx, int* rank, int* degs_s) {
    __shared__ int h[NDEG_];
    __shared__ int base[NDEG_];
    const int i = blockIdx.x * 256 + threadIdx.x;
    const int d = (i < N_ATOMS) ? deg[i] : -1;
    if (threadIdx.x < NDEG_) h[threadIdx.x] = 0;
    __syncthreads();
    int intra = 0;
    if (i < N_ATOMS) intra = atomicAdd(&h[d], 1);            // LDS atomic
    __syncthreads();
    if (threadIdx.x < NDEG_ && h[threadIdx.x] > 0)
        base[threadIdx.x] = atomicAdd(&ctr[5 + threadIdx.x], h[threadIdx.x]);
    __syncthreads();
    if (i < N_ATOMS) {
        const int p = ctr[10 + d] + base[d] + intra;
        idx[p] = i;
        rank[i] = p;
        degs_s[p] = d;
    }
}

__launch_bounds__(256)
__global__ void nbrprep_kernel(const int* __restrict__ nbr, const int* __restrict__ rank,
                               int4* __restrict__ nbrs_s) {
    const int i = blockIdx.x * 256 + threadIdx.x;
    if (i >= N_ATOMS) return;
    const int p = rank[i];
    const int4 nb = *reinterpret_cast<const int4*>(nbr + (size_t)i * MAX_D);
    nbrs_s[p] = make_int4(rank[nb.x], rank[nb.y], rank[nb.z], rank[nb.w]);
}

// ===================== gather: masked neighbor sum (sorted space) =====================
template<int FI, bool FIRST>
__launch_bounds__(256)
__global__ void gather_s(const float* __restrict__ x,
                         const int4*  __restrict__ nbrs,
                         const int*   __restrict__ degs_s,
                         const int*   __restrict__ idx,
                         float*       __restrict__ nsum,
                         int p0, int total /* = cnt*FI */)
{
    for (int e = blockIdx.x * 256 + threadIdx.x; e < total; e += gridDim.x * 256) {
        const int pl = e / FI, f = e - pl * FI;
        const int p = p0 + pl;
        const int d = degs_s[p];
        float s = 0.f;
        if (d > 0) {
            const int4 nb = nbrs[p];
            if (FIRST) {
                s += x[(size_t)idx[nb.x] * FI + f];
                if (d > 1) s += x[(size_t)idx[nb.y] * FI + f];
                if (d > 2) s += x[(size_t)idx[nb.z] * FI + f];
                if (d > 3) s += x[(size_t)idx[nb.w] * FI + f];
            } else {
                s += x[(size_t)nb.x * FI + f];
                if (d > 1) s += x[(size_t)nb.y * FI + f];
                if (d > 2) s += x[(size_t)nb.z * FI + f];
                if (d > 3) s += x[(size_t)nb.w * FI + f];
            }
        }
        nsum[e] = s;
    }
}

// ===================== affine: out_s[p] = selu(x@Ws[d] + nsum@Wn[d] + b[d]) =====================
// Degree-uniform tiles; wave-uniform weight pointer -> scalar loads; no LDS.
template<int FI, int FO, bool FIRST>
__launch_bounds__(256)
__global__ void affine_s(const float* __restrict__ x,
                         const float* __restrict__ nsum,
                         const float* __restrict__ Ws,
                         const float* __restrict__ Wn,
                         const float* __restrict__ bias,
                         const int*   __restrict__ degs_s,
                         const int*   __restrict__ idx,
                         float*       __restrict__ outs,
                         int p0)
{
    const int tile_base = p0 + blockIdx.x * AT;
    const int dfirst = degs_s[tile_base];
    if (dfirst < 0) return;                       // whole tile is padding
    const int d = __builtin_amdgcn_readfirstlane(dfirst);

    const float* __restrict__ wsd = Ws + d * FI * FO;
    const float* __restrict__ wnd = Wn + d * FI * FO;
    const float* __restrict__ bb  = bias + d * FO;

    const int p = tile_base + threadIdx.x;

    float acc[FO];
    #pragma unroll
    for (int o = 0; o < FO; ++o) acc[o] = bb[o];

    const float* __restrict__ xr;
    if (FIRST) {
        int a = idx[p];
        if (a < 0) a = 0;                         // padding lane: dummy row, result discarded
        xr = x + (size_t)a * FI;
    } else {
        xr = x + (size_t)p * FI;
    }
    const float* __restrict__ nr = nsum + (size_t)(p - p0) * FI;

    for (int f = 0; f < FI; ++f) {
        const float xv = xr[f];
        const float nv = nr[f];
        const float* __restrict__ wsf = wsd + f * FO;
        const float* __restrict__ wnf = wnd + f * FO;
        #pragma unroll
        for (int o = 0; o < FO; ++o)
            acc[o] = fmaf(xv, wsf[o], fmaf(nv, wnf[o], acc[o]));
    }

    float* __restrict__ orow = outs + (size_t)p * FO;
    #pragma unroll
    for (int o = 0; o < FO; ++o) orow[o] = selu_f(acc[o]);
}

template<int FI, int FO, bool FIRST>
static void run_conv(const float* x, const float* Ws, const float* Wn, const float* b,
                     const int4* nbrs_s, const int* degs_s, const int* idx,
                     float* outs, float* nscr, hipStream_t stream)
{
    const int cap = ((NSCR_FLOATS / FI) / AT) * AT;   // atoms per chunk (multiple of AT)
    for (int p0 = 0; p0 < PADCAP; p0 += cap) {
        const int cnt = (PADCAP - p0) < cap ? (PADCAP - p0) : cap;
        const int gtot = cnt * FI;
        int gblocks = (gtot + 255) / 256; if (gblocks > 8192) gblocks = 8192;
        gather_s<FI, FIRST><<<gblocks, 256, 0, stream>>>(x, nbrs_s, degs_s, idx, nscr, p0, gtot);
        affine_s<FI, FO, FIRST><<<cnt / AT, AT, 0, stream>>>(x, nscr, Ws, Wn, b, degs_s, idx, outs, p0);
    }
}

// ===================== GraphGather readout + softmax head =====================
__launch_bounds__(64)
__global__ void readout_kernel(const float* __restrict__ x4s,
                               const int*   __restrict__ rank,
                               const int*   __restrict__ mem,
                               const float* __restrict__ Wd2,
                               const float* __restrict__ bd2,
                               float*       __restrict__ p)
{
    const int g = blockIdx.x;
    const int t = threadIdx.x;

    int lo = 0, hi = N_ATOMS;                    // lower_bound(g)
    while (lo < hi) { int mid = (lo + hi) >> 1; if (mem[mid] < g) lo = mid + 1; else hi = mid; }
    int lo2 = lo, hi2 = N_ATOMS;                 // lower_bound(g+1)
    while (lo2 < hi2) { int mid = (lo2 + hi2) >> 1; if (mem[mid] < g + 1) lo2 = mid + 1; else hi2 = mid; }

    __shared__ float r[72];
    if (t < 36) {
        float s = 0.f, m = -3.4e38f;
        for (int a = lo; a < lo2; ++a) {
            const int rr = rank[a];
            float v = x4s[(size_t)rr * 36 + t];
            s += v;
            m = fmaxf(m, v);
        }
        if (lo2 == lo) m = 0.f;                  // empty graph -> 0
        r[t]      = selu_f(s);
        r[36 + t] = selu_f(m);
    }
    __syncthreads();
    if (t < 24) {
        float acc = bd2[t];
        #pragma unroll
        for (int f = 0; f < 72; ++f) acc += r[f] * Wd2[f * 24 + t];
        float part = __shfl_xor(acc, 1);
        p[g * 24 + t] = 1.f / (1.f + __expf(part - acc));
    }
}

__launch_bounds__(256)
__global__ void dense1_kernel(const float* __restrict__ p,
                              const float* __restrict__ Wl1,
                              const float* __restrict__ bl1,
                              float*       __restrict__ y1)
{
    const int idx = blockIdx.x * 256 + threadIdx.x;
    if (idx >= B_GR * 96) return;
    const int row = idx / 96, c = idx - row * 96;
    float acc = bl1[c];
    const float* pr = p + row * 24;
    #pragma unroll
    for (int f = 0; f < 24; ++f) acc += pr[f] * Wl1[f * 96 + c];
    y1[idx] = acc;
}

template<int C>
__launch_bounds__(256)
__global__ void stats_kernel(const float* __restrict__ y, float* __restrict__ st)
{
    const int c = blockIdx.x;
    float s = 0.f, q = 0.f;
    for (int r = threadIdx.x; r < B_GR; r += 256) {
        const float v = y[r * C + c];
        s += v; q += v * v;
    }
    __shared__ float ss[256], qq[256];
    ss[threadIdx.x] = s; qq[threadIdx.x] = q;
    __syncthreads();
    for (int off = 128; off > 0; off >>= 1) {
        if (threadIdx.x < off) {
            ss[threadIdx.x] += ss[threadIdx.x + off];
            qq[threadIdx.x] += qq[threadIdx.x + off];
        }
        __syncthreads();
    }
    if (threadIdx.x == 0) {
        const float mean = ss[0] / (float)B_GR;
        const float var  = qq[0] / (float)B_GR - mean * mean;
        st[c]     = mean;
        st[C + c] = rsqrtf(var + 1e-5f);
    }
}

__launch_bounds__(256)
__global__ void dense2_kernel(const float* __restrict__ y1,
                              const float* __restrict__ st1,
                              const float* __restrict__ g1,
                              const float* __restrict__ be1,
                              const float* __restrict__ Wl2,
                              const float* __restrict__ bl2,
                              float*       __restrict__ y2)
{
    __shared__ float h[4 * 96];
    const int r0 = blockIdx.x * 4;
    for (int e = threadIdx.x; e < 4 * 96; e += 256) {
        const int rr = e / 96, c = e - rr * 96;
        float v = y1[(r0 + rr) * 96 + c];
        v = (v - st1[c]) * st1[96 + c] * g1[c] + be1[c];
        h[e] = fmaxf(v, 0.f);
    }
    __syncthreads();
    for (int e = threadIdx.x; e < 4 * 63; e += 256) {
        const int rr = e / 63, o = e - rr * 63;
        float acc = bl2[o];
        #pragma unroll
        for (int f = 0; f < 96; ++f) acc += h[rr * 96 + f] * Wl2[f * 63 + o];
        y2[(r0 + rr) * 63 + o] = acc;
    }
}

__launch_bounds__(320)
__global__ void dense3_kernel(const float* __restrict__ y2,
                              const float* __restrict__ st2,
                              const float* __restrict__ g2,
                              const float* __restrict__ be2,
                              const float* __restrict__ Wl3,
                              const float* __restrict__ bl3,
                              float*       __restrict__ out)
{
    __shared__ float h[2 * 63];
    const int r0 = blockIdx.x * 2;
    for (int e = threadIdx.x; e < 2 * 63; e += 320) {
        const int rr = e / 63, c = e - rr * 63;
        float v = y2[(r0 + rr) * 63 + c];
        v = (v - st2[c]) * st2[63 + c] * g2[c] + be2[c];
        h[e] = fmaxf(v, 0.f);
    }
    __syncthreads();
    for (int e = threadIdx.x; e < 2 * 138; e += 320) {
        const int rr = e / 138, o = e - rr * 138;
        float acc = bl3[o];
        #pragma unroll
        for (int f = 0; f < 63; ++f) acc += h[rr * 63 + f] * Wl3[f * 138 + o];
        out[(r0 + rr) * 138 + o] = 1.f / (1.f + __expf(-acc));
    }
}

extern "C" void kernel_launch(void* const* d_in, const int* in_sizes, int n_in,
                              void* d_out, int out_size, void* d_ws, size_t ws_size,
                              hipStream_t stream)
{
    (void)in_sizes; (void)n_in; (void)out_size; (void)ws_size;

    const float* af  = (const float*)d_in[0];
    const float* Ws1 = (const float*)d_in[1];
    const float* Wn1 = (const float*)d_in[2];
    const float* b1  = (const float*)d_in[3];
    const float* Ws2 = (const float*)d_in[4];
    const float* Wn2 = (const float*)d_in[5];
    const float* b2  = (const float*)d_in[6];
    const float* Ws3 = (const float*)d_in[7];
    const float* Wn3 = (const float*)d_in[8];
    const float* b3  = (const float*)d_in[9];
    const float* Ws4 = (const float*)d_in[10];
    const float* Wn4 = (const float*)d_in[11];
    const float* b4  = (const float*)d_in[12];
    const float* Wd2 = (const float*)d_in[13];
    const float* bd2 = (const float*)d_in[14];
    const float* Wl1 = (const float*)d_in[15];
    const float* bl1 = (const float*)d_in[16];
    const float* g1  = (const float*)d_in[17];
    const float* be1 = (const float*)d_in[18];
    const float* Wl2 = (const float*)d_in[19];
    const float* bl2 = (const float*)d_in[20];
    const float* g2  = (const float*)d_in[21];
    const float* be2 = (const float*)d_in[22];
    const float* Wl3 = (const float*)d_in[23];
    const float* bl3 = (const float*)d_in[24];
    const int*   nbr = (const int*)d_in[25];
    const int*   deg = (const int*)d_in[26];
    const int*   mem = (const int*)d_in[27];

    float* ws = (float*)d_ws;
    float* bufA = ws;                                   // PADCAP*27
    float* bufB = bufA + (size_t)PADCAP * 27;           // PADCAP*36
    float* nscr = bufB + (size_t)PADCAP * 36;           // NSCR_FLOATS
    int*   idx    = (int*)(nscr + NSCR_FLOATS);         // PADCAP
    int*   rank   = idx + PADCAP;                       // N_ATOMS
    int*   degs_s = rank + N_ATOMS;                     // PADCAP
    int4*  nbrs_s = (int4*)(degs_s + PADCAP);           // PADCAP int4
    int*   ctr    = (int*)(nbrs_s + PADCAP);            // 16 ints

    float* x1 = bufA;
    float* x2 = bufB;
    float* x3 = bufA;
    float* x4 = bufB;
    float* p   = bufA;                       // B*24  (x3 dead after conv4)
    float* y1  = bufA + 393216;              // B*96
    float* y2  = bufA + 393216 + 1572864;    // B*63
    float* st1 = bufA + 393216 + 1572864 + 1032192;     // 192
    float* st2 = st1 + 192;                              // 126

    // ---- degree-sort prep (permutation may vary run-to-run; per-atom math identical) ----
    zero_kernel<<<1, 16, 0, stream>>>(ctr);
    fill_kernel<<<PADCAP / 256, 256, 0, stream>>>(idx, degs_s);
    hist_kernel<<<1024, 256, 0, stream>>>(deg, ctr);
    offsets_kernel<<<1, 1, 0, stream>>>(ctr);
    scatter_kernel<<<(N_ATOMS + 255) / 256, 256, 0, stream>>>(deg, ctr, idx, rank, degs_s);
    nbrprep_kernel<<<(N_ATOMS + 255) / 256, 256, 0, stream>>>(nbr, rank, nbrs_s);

    // ---- conv stack (sorted feature space) ----
    run_conv<75, 15, true >(af, Ws1, Wn1, b1, nbrs_s, degs_s, idx, x1, nscr, stream);
    run_conv<15, 20, false>(x1, Ws2, Wn2, b2, nbrs_s, degs_s, idx, x2, nscr, stream);
    run_conv<20, 27, false>(x2, Ws3, Wn3, b3, nbrs_s, degs_s, idx, x3, nscr, stream);
    run_conv<27, 36, false>(x3, Ws4, Wn4, b4, nbrs_s, degs_s, idx, x4, nscr, stream);

    readout_kernel<<<B_GR, 64, 0, stream>>>(x4, rank, mem, Wd2, bd2, p);

    dense1_kernel<<<(B_GR * 96) / 256, 256, 0, stream>>>(p, Wl1, bl1, y1);
    stats_kernel<96><<<96, 256, 0, stream>>>(y1, st1);
    dense2_kernel<<<B_GR / 4, 256, 0, stream>>>(y1, st1, g1, be1, Wl2, bl2, y2);
    stats_kernel<63><<<63, 256, 0, stream>>>(y2, st2);
    dense3_kernel<<<B_GR / 2, 320, 0, stream>>>(y2, st2, g2, be2, Wl3, bl3, (float*)d_out);
}